// Round 6
// baseline (436.551 us; speedup 1.0000x reference)
//
#include <hip/hip_runtime.h>
#include <hip/hip_bf16.h>
#include <hip/hip_cooperative_groups.h>
namespace cg = cooperative_groups;

// B=4, S=256, H=768, P=54.
// out[b,i,j,p] = valid ? relu(ha[b,i]+hb[b,j]+bp1) . Wp2[p] + bp2[p] : 0
// valid = cand[i] & cand[j] & i!=j; cand = (relu(x W1^T + b1) . W2[0] + b2[0]) > 0.5
// cand rate ~1% -> sparse pairs.
// R1: per-CU BW bound hab -> k-split. R2: split-K=4 gemm, stride-68 LDS.
// R3: 139.8us best; top-5 = harness ws-poison fills (44us, fixed).
// R4: multi-change regression. R5: 147.4, 4 dispatches.
// R6: ONE change — fuse all 4 phases into one cooperative kernel (768 blk,
//     grid.sync between phases; phase code verbatim from R5). Fallback to
//     R5 4-kernel path if cooperative launch is rejected.

#define M_ROWS 1024
#define HDIM 768
#define PDIM 54
#define MAXC 256
#define KSPLIT 4
#define KSEG (HDIM / KSPLIT)  // 192
#define GRID_C 768            // cooperative grid: 3 blocks/CU

// ---- workspace layout (bytes) ----
#define CANDCNT_OFF  0
#define CANDIDX_OFF  1024
#define CANDSLOT_OFF 8192
#define HA_OFF       16384
#define HB_OFF       (16384 + 786432)
#define HPART_OFF    (16384 + 2 * 786432)

union SMem {
    struct { float As[16][68]; float Bs[16][68]; } g;               // 8704 B
    struct { float wred[4]; } s;
    struct { float v[HDIM]; float red[4][PDIM + 2]; int plist[256]; int pcnt; } p;
};

// ================= fused cooperative pipeline =================
__global__ __launch_bounds__(256) void fused_kernel(
    const float* __restrict__ x, const float* __restrict__ W1,
    const float* __restrict__ b1, const float* __restrict__ w2row,
    const float* __restrict__ b2, const float* __restrict__ Wp1,
    const float* __restrict__ bp1, const float* __restrict__ Wp2,
    const float* __restrict__ bp2,
    float* __restrict__ hpart, int* __restrict__ candCnt,
    int* __restrict__ candIdx, int* __restrict__ candSlot,
    float* __restrict__ ha, float* __restrict__ hb,
    float* __restrict__ out)
{
    __shared__ SMem sm;
    cg::grid_group grid = cg::this_grid();
    const int bid = blockIdx.x;
    const int t   = threadIdx.x;

    // ---------- phase 1: split-K GEMM (verbatim R5 inner) ----------
    if (bid == 0 && t == 0) *candCnt = 0;
    {
        const int mt = bid & 15;          // 16
        const int nt = (bid >> 4) % 12;   // 12
        const int z  = bid / 192;         // 4
        const int m0 = mt * 64, n0 = nt * 64, kb = z * KSEG;
        const int tm = t & 15, tn = t >> 4;
        const int r  = t >> 2, c4 = (t & 3) * 4;

        float acc[4][4] = {};
        for (int k0 = kb; k0 < kb + KSEG; k0 += 16) {
            float4 av = *(const float4*)(x  + (size_t)(m0 + r) * HDIM + k0 + c4);
            float4 bv = *(const float4*)(W1 + (size_t)(n0 + r) * HDIM + k0 + c4);
            sm.g.As[c4+0][r] = av.x; sm.g.As[c4+1][r] = av.y; sm.g.As[c4+2][r] = av.z; sm.g.As[c4+3][r] = av.w;
            sm.g.Bs[c4+0][r] = bv.x; sm.g.Bs[c4+1][r] = bv.y; sm.g.Bs[c4+2][r] = bv.z; sm.g.Bs[c4+3][r] = bv.w;
            __syncthreads();
            #pragma unroll
            for (int kk = 0; kk < 16; ++kk) {
                float a[4], b[4];
                *(float4*)a = *(const float4*)&sm.g.As[kk][tm * 4];
                *(float4*)b = *(const float4*)&sm.g.Bs[kk][tn * 4];
                #pragma unroll
                for (int i = 0; i < 4; ++i)
                    #pragma unroll
                    for (int j = 0; j < 4; ++j)
                        acc[i][j] += a[i] * b[j];
            }
            __syncthreads();
        }
        float* dst = hpart + (size_t)z * (M_ROWS * HDIM);
        #pragma unroll
        for (int i = 0; i < 4; ++i) {
            float4 v = make_float4(acc[i][0], acc[i][1], acc[i][2], acc[i][3]);
            *(float4*)(dst + (size_t)(m0 + tm * 4 + i) * HDIM + n0 + tn * 4) = v;
        }
    }
    grid.sync();

    // ---------- phase 2: span + cand (R5 span_cand, grid-strided) ----------
    for (int m = bid; m < M_ROWS; m += GRID_C) {
        float p = 0.f;
        for (int n = t; n < HDIM; n += 256) {
            float v = hpart[(size_t)m * HDIM + n]
                    + hpart[(size_t)(M_ROWS * HDIM) + (size_t)m * HDIM + n]
                    + hpart[(size_t)(2 * M_ROWS * HDIM) + (size_t)m * HDIM + n]
                    + hpart[(size_t)(3 * M_ROWS * HDIM) + (size_t)m * HDIM + n];
            v += b1[n];
            v = v > 0.f ? v : 0.f;
            p += v * w2row[n];
        }
        #pragma unroll
        for (int off = 32; off > 0; off >>= 1) p += __shfl_down(p, off, 64);
        if ((t & 63) == 0) sm.s.wred[t >> 6] = p;
        __syncthreads();
        if (t == 0) {
            float s = sm.s.wred[0] + sm.s.wred[1] + sm.s.wred[2] + sm.s.wred[3] + b2[0];
            if (s > 0.5f) {
                int sl = atomicAdd(candCnt, 1);
                if (sl < MAXC) { candIdx[sl] = m; candSlot[m] = sl; }
                else candSlot[m] = -1;
            } else {
                candSlot[m] = -1;
            }
        }
        __syncthreads();
    }
    grid.sync();

    // ---------- phase 3: hab, register-resident Wp1 (R5 inner) ----------
    {
        int nc = *candCnt; if (nc > MAXC) nc = MAXC;
        const int kc   = bid % 96;
        const int s0   = bid / 96;          // 0..7: slot start, stride 8
        const int kk   = t >> 5;
        const int lane = t & 31;
        const int k    = kc * 8 + kk;

        const float* wr = Wp1 + (size_t)k * (2 * HDIM);
        float4 wa[6], wb[6];
        #pragma unroll
        for (int c = 0; c < 6; ++c) {
            wa[c] = *(const float4*)(wr + c * 128 + lane * 4);
            wb[c] = *(const float4*)(wr + HDIM + c * 128 + lane * 4);
        }
        for (int slot = s0; slot < nc; slot += 8) {
            int row = candIdx[slot];
            const float* xr = x + (size_t)row * HDIM;
            float sa = 0.f, sb = 0.f;
            #pragma unroll
            for (int c = 0; c < 6; ++c) {
                float4 xv = *(const float4*)(xr + c * 128 + lane * 4);
                sa += wa[c].x*xv.x + wa[c].y*xv.y + wa[c].z*xv.z + wa[c].w*xv.w;
                sb += wb[c].x*xv.x + wb[c].y*xv.y + wb[c].z*xv.z + wb[c].w*xv.w;
            }
            #pragma unroll
            for (int off = 16; off > 0; off >>= 1) {
                sa += __shfl_down(sa, off, 32);
                sb += __shfl_down(sb, off, 32);
            }
            if (lane == 0) {
                ha[(size_t)slot * HDIM + k] = sa;
                hb[(size_t)slot * HDIM + k] = sb;
            }
        }
    }
    grid.sync();

    // ---------- phase 4: zero + pair scan + logits (R5 inner, chunked) ----------
    for (int chunk = bid; chunk < 1024; chunk += GRID_C) {
        float* outb = out + (size_t)chunk * 256 * PDIM;   // 13824 f32 = 3456 float4
        float4 z4 = make_float4(0.f, 0.f, 0.f, 0.f);
        #pragma unroll
        for (int q = 0; q < 14; ++q) {
            int idx4 = q * 256 + t;
            if (idx4 < 3456) *(float4*)(outb + (size_t)idx4 * 4) = z4;
        }
        if (t == 0) sm.p.pcnt = 0;
        __syncthreads();

        {
            int idx = chunk * 256 + t;  // b*65536 + i*256 + j
            int b = idx >> 16;
            int i = (idx >> 8) & 255;
            int j = idx & 255;
            if (i != j && candSlot[b * 256 + i] >= 0 && candSlot[b * 256 + j] >= 0) {
                int p = atomicAdd(&sm.p.pcnt, 1);
                sm.p.plist[p] = idx;
            }
        }
        __syncthreads();
        const int np = sm.p.pcnt;

        for (int p = 0; p < np; ++p) {
            int idx = sm.p.plist[p];
            int b = idx >> 16;
            int i = (idx >> 8) & 255;
            int j = idx & 255;
            int si = candSlot[b * 256 + i];
            int sj = candSlot[b * 256 + j];
            if (t < 192) {
                float4 a4 = *(const float4*)(ha + (size_t)si * HDIM + t * 4);
                float4 b4 = *(const float4*)(hb + (size_t)sj * HDIM + t * 4);
                float4 c4 = *(const float4*)(bp1 + t * 4);
                float4 r;
                r.x = a4.x + b4.x + c4.x; r.x = r.x > 0.f ? r.x : 0.f;
                r.y = a4.y + b4.y + c4.y; r.y = r.y > 0.f ? r.y : 0.f;
                r.z = a4.z + b4.z + c4.z; r.z = r.z > 0.f ? r.z : 0.f;
                r.w = a4.w + b4.w + c4.w; r.w = r.w > 0.f ? r.w : 0.f;
                *(float4*)(sm.p.v + t * 4) = r;
            }
            __syncthreads();
            if (t < 216) {
                int pp  = t % PDIM;
                int seg = t / PDIM;
                const float* w  = Wp2 + (size_t)pp * HDIM + seg * 192;
                const float* vv = sm.p.v + seg * 192;
                float s = 0.f;
                for (int h = 0; h < 192; h += 4) {
                    float4 a  = *(const float4*)(vv + h);
                    float4 b2v = *(const float4*)(w + h);
                    s += a.x * b2v.x + a.y * b2v.y + a.z * b2v.z + a.w * b2v.w;
                }
                sm.p.red[seg][pp] = s;
            }
            __syncthreads();
            if (t < PDIM)
                out[(size_t)idx * PDIM + t] = sm.p.red[0][t] + sm.p.red[1][t]
                                            + sm.p.red[2][t] + sm.p.red[3][t] + bp2[t];
            __syncthreads();
        }
    }
}

// ================= fallback path: R5 kernels verbatim =================
__global__ __launch_bounds__(256) void gemm_k_kernel(
    const float* __restrict__ x, const float* __restrict__ W1,
    float* __restrict__ hpart, int* __restrict__ candCnt)
{
    __shared__ float As[16][68];
    __shared__ float Bs[16][68];
    if (threadIdx.x == 0 && blockIdx.x == 0 && blockIdx.y == 0 && blockIdx.z == 0)
        *candCnt = 0;
    const int m0 = blockIdx.x * 64;
    const int n0 = blockIdx.y * 64;
    const int kb = blockIdx.z * KSEG;
    const int t  = threadIdx.x;
    const int tm = t & 15, tn = t >> 4;
    const int r  = t >> 2, c4 = (t & 3) * 4;
    float acc[4][4] = {};
    for (int k0 = kb; k0 < kb + KSEG; k0 += 16) {
        float4 av = *(const float4*)(x  + (size_t)(m0 + r) * HDIM + k0 + c4);
        float4 bv = *(const float4*)(W1 + (size_t)(n0 + r) * HDIM + k0 + c4);
        As[c4+0][r] = av.x; As[c4+1][r] = av.y; As[c4+2][r] = av.z; As[c4+3][r] = av.w;
        Bs[c4+0][r] = bv.x; Bs[c4+1][r] = bv.y; Bs[c4+2][r] = bv.z; Bs[c4+3][r] = bv.w;
        __syncthreads();
        #pragma unroll
        for (int kk = 0; kk < 16; ++kk) {
            float a[4], b[4];
            *(float4*)a = *(const float4*)&As[kk][tm * 4];
            *(float4*)b = *(const float4*)&Bs[kk][tn * 4];
            #pragma unroll
            for (int i = 0; i < 4; ++i)
                #pragma unroll
                for (int j = 0; j < 4; ++j)
                    acc[i][j] += a[i] * b[j];
        }
        __syncthreads();
    }
    float* dst = hpart + (size_t)blockIdx.z * (M_ROWS * HDIM);
    #pragma unroll
    for (int i = 0; i < 4; ++i) {
        float4 v = make_float4(acc[i][0], acc[i][1], acc[i][2], acc[i][3]);
        *(float4*)(dst + (size_t)(m0 + tm * 4 + i) * HDIM + n0 + tn * 4) = v;
    }
}

__global__ __launch_bounds__(256) void span_cand_kernel(
    const float* __restrict__ hpart, const float* __restrict__ b1,
    const float* __restrict__ w2row, const float* __restrict__ b2,
    int* __restrict__ candCount, int* __restrict__ candIdx,
    int* __restrict__ candSlot)
{
    const int m = blockIdx.x;
    const int t = threadIdx.x;
    float p = 0.f;
    for (int n = t; n < HDIM; n += 256) {
        float v = hpart[(size_t)m * HDIM + n]
                + hpart[(size_t)(M_ROWS * HDIM) + (size_t)m * HDIM + n]
                + hpart[(size_t)(2 * M_ROWS * HDIM) + (size_t)m * HDIM + n]
                + hpart[(size_t)(3 * M_ROWS * HDIM) + (size_t)m * HDIM + n];
        v += b1[n];
        v = v > 0.f ? v : 0.f;
        p += v * w2row[n];
    }
    __shared__ float wred[4];
    #pragma unroll
    for (int off = 32; off > 0; off >>= 1) p += __shfl_down(p, off, 64);
    if ((t & 63) == 0) wred[t >> 6] = p;
    __syncthreads();
    if (t == 0) {
        float s = wred[0] + wred[1] + wred[2] + wred[3] + b2[0];
        if (s > 0.5f) {
            int sl = atomicAdd(candCount, 1);
            if (sl < MAXC) { candIdx[sl] = m; candSlot[m] = sl; }
            else candSlot[m] = -1;
        } else {
            candSlot[m] = -1;
        }
    }
}

__global__ __launch_bounds__(256) void hab_kernel(
    const float* __restrict__ x, const float* __restrict__ Wp1,
    const int* __restrict__ candCount, const int* __restrict__ candIdx,
    float* __restrict__ ha, float* __restrict__ hb)
{
    int nc = *candCount; if (nc > MAXC) nc = MAXC;
    const int kk   = threadIdx.x >> 5;
    const int lane = threadIdx.x & 31;
    const int k    = blockIdx.x * 8 + kk;
    const float* wr = Wp1 + (size_t)k * (2 * HDIM);
    float4 wa[6], wb[6];
    #pragma unroll
    for (int c = 0; c < 6; ++c) {
        wa[c] = *(const float4*)(wr + c * 128 + lane * 4);
        wb[c] = *(const float4*)(wr + HDIM + c * 128 + lane * 4);
    }
    for (int slot = 0; slot < nc; ++slot) {
        int row = candIdx[slot];
        const float* xr = x + (size_t)row * HDIM;
        float sa = 0.f, sb = 0.f;
        #pragma unroll
        for (int c = 0; c < 6; ++c) {
            float4 xv = *(const float4*)(xr + c * 128 + lane * 4);
            sa += wa[c].x*xv.x + wa[c].y*xv.y + wa[c].z*xv.z + wa[c].w*xv.w;
            sb += wb[c].x*xv.x + wb[c].y*xv.y + wb[c].z*xv.z + wb[c].w*xv.w;
        }
        #pragma unroll
        for (int off = 16; off > 0; off >>= 1) {
            sa += __shfl_down(sa, off, 32);
            sb += __shfl_down(sb, off, 32);
        }
        if (lane == 0) {
            ha[(size_t)slot * HDIM + k] = sa;
            hb[(size_t)slot * HDIM + k] = sb;
        }
    }
}

__global__ __launch_bounds__(256) void pair_kernel(
    const float* __restrict__ ha, const float* __restrict__ hb,
    const float* __restrict__ bp1, const float* __restrict__ Wp2,
    const float* __restrict__ bp2, const int* __restrict__ candSlot,
    float* __restrict__ out)
{
    __shared__ int plist[512];
    __shared__ int pcnt;
    __shared__ float v[HDIM];
    __shared__ float red[4][PDIM + 2];
    const int t = threadIdx.x;
    float* outb = out + (size_t)blockIdx.x * 512 * PDIM;
    float4 z = make_float4(0.f, 0.f, 0.f, 0.f);
    #pragma unroll
    for (int q = 0; q < 27; ++q)
        *(float4*)(outb + (size_t)(q * 256 + t) * 4) = z;
    if (t == 0) pcnt = 0;
    __syncthreads();
    #pragma unroll
    for (int q = 0; q < 2; ++q) {
        int idx = blockIdx.x * 512 + q * 256 + t;
        int b = idx >> 16;
        int i = (idx >> 8) & 255;
        int j = idx & 255;
        if (i != j && candSlot[b * 256 + i] >= 0 && candSlot[b * 256 + j] >= 0) {
            int p = atomicAdd(&pcnt, 1);
            plist[p] = idx;
        }
    }
    __syncthreads();
    const int np = pcnt;
    for (int p = 0; p < np; ++p) {
        int idx = plist[p];
        int b = idx >> 16;
        int i = (idx >> 8) & 255;
        int j = idx & 255;
        int si = candSlot[b * 256 + i];
        int sj = candSlot[b * 256 + j];
        if (t < 192) {
            float4 a4 = *(const float4*)(ha + (size_t)si * HDIM + t * 4);
            float4 b4 = *(const float4*)(hb + (size_t)sj * HDIM + t * 4);
            float4 c4 = *(const float4*)(bp1 + t * 4);
            float4 r;
            r.x = a4.x + b4.x + c4.x; r.x = r.x > 0.f ? r.x : 0.f;
            r.y = a4.y + b4.y + c4.y; r.y = r.y > 0.f ? r.y : 0.f;
            r.z = a4.z + b4.z + c4.z; r.z = r.z > 0.f ? r.z : 0.f;
            r.w = a4.w + b4.w + c4.w; r.w = r.w > 0.f ? r.w : 0.f;
            *(float4*)(v + t * 4) = r;
        }
        __syncthreads();
        if (t < 216) {
            int pp  = t % PDIM;
            int seg = t / PDIM;
            const float* w  = Wp2 + (size_t)pp * HDIM + seg * 192;
            const float* vv = v + seg * 192;
            float s = 0.f;
            for (int h = 0; h < 192; h += 4) {
                float4 a  = *(const float4*)(vv + h);
                float4 b2 = *(const float4*)(w + h);
                s += a.x * b2.x + a.y * b2.y + a.z * b2.z + a.w * b2.w;
            }
            red[seg][pp] = s;
        }
        __syncthreads();
        if (t < PDIM)
            out[(size_t)idx * PDIM + t] = red[0][t] + red[1][t] + red[2][t] + red[3][t] + bp2[t];
        __syncthreads();
    }
}

extern "C" void kernel_launch(void* const* d_in, const int* in_sizes, int n_in,
                              void* d_out, int out_size, void* d_ws, size_t ws_size,
                              hipStream_t stream) {
    const float* x   = (const float*)d_in[0];
    const float* W1s = (const float*)d_in[1];
    const float* b1s = (const float*)d_in[2];
    const float* W2s = (const float*)d_in[3];
    const float* b2s = (const float*)d_in[4];
    const float* Wp1 = (const float*)d_in[5];
    const float* bp1 = (const float*)d_in[6];
    const float* Wp2 = (const float*)d_in[7];
    const float* bp2 = (const float*)d_in[8];

    char* ws = (char*)d_ws;
    int*   candCnt  = (int*)(ws + CANDCNT_OFF);
    int*   candIdx  = (int*)(ws + CANDIDX_OFF);
    int*   candSlot = (int*)(ws + CANDSLOT_OFF);
    float* ha       = (float*)(ws + HA_OFF);
    float* hb       = (float*)(ws + HB_OFF);
    float* hpart    = (float*)(ws + HPART_OFF);
    float* out = (float*)d_out;

    void* kargs[] = {
        (void*)&x, (void*)&W1s, (void*)&b1s, (void*)&W2s, (void*)&b2s,
        (void*)&Wp1, (void*)&bp1, (void*)&Wp2, (void*)&bp2,
        (void*)&hpart, (void*)&candCnt, (void*)&candIdx, (void*)&candSlot,
        (void*)&ha, (void*)&hb, (void*)&out
    };
    hipError_t err = hipLaunchCooperativeKernel((const void*)fused_kernel,
                                                dim3(GRID_C), dim3(256),
                                                kargs, 0, stream);
    if (err != hipSuccess) {
        // fallback: proven R5 4-kernel path (identical math)
        dim3 g(M_ROWS / 64, HDIM / 64, KSPLIT);
        gemm_k_kernel<<<g, 256, 0, stream>>>(x, W1s, hpart, candCnt);
        span_cand_kernel<<<M_ROWS, 256, 0, stream>>>(hpart, b1s, W2s, b2s,
                                                     candCnt, candIdx, candSlot);
        hab_kernel<<<96, 256, 0, stream>>>(x, Wp1, candCnt, candIdx, ha, hb);
        pair_kernel<<<512, 256, 0, stream>>>(ha, hb, bp1, Wp2, bp2, candSlot, out);
    }
}

// Round 7
// 137.471 us; speedup vs baseline: 3.1756x; 3.1756x over previous
//
#include <hip/hip_runtime.h>
#include <hip/hip_bf16.h>

// B=4, S=256, H=768, P=54.
// out[b,i,j,p] = valid ? relu(ha[b,i]+hb[b,j]+bp1) . Wp2[p] + bp2[p] : 0
// valid = cand[i] & cand[j] & i!=j; cand = (relu(x W1^T + b1) . W2[0] + b2[0]) > 0.5
// cand rate ~1% -> sparse pairs.
// R1: per-CU-BW-bound hab -> k-split. R2: split-K=4 gemm (768 blk), stride-68 LDS.
// R3: 139.8us BEST. R4 (+11) / R5 (+7.6): unattributed multi-change regressions.
// R6: cooperative grid.sync fusion = 340us DISASTER (XCD-L2 non-coherence makes
//     grid.sync flush/serialize; 264 GB/s latency-bound). Lesson: no coop fusion.
// R7: restore R3 verbatim; ONE change = fold counter zeroing into gemm_k
//     (drops the 8KB memset dispatch). Re-anchor.

#define M_ROWS 1024
#define HDIM 768
#define PDIM 54
#define MAXC 256            // candidate slot cap (actual nc ~27)
#define KCHUNK 16
#define NKC (HDIM / KCHUNK) // 48
#define KSPLIT 4
#define KSEG (HDIM / KSPLIT) // 192

// ---- workspace layout (bytes) ---- (R3-proven)
#define CANDCNT_OFF  0
#define PAIRCNT_OFF  4
#define CANDIDX_OFF  8192        // MAXC int
#define CANDSLOT_OFF 12288       // 1024 int (fully written each call)
#define PAIR_OFF     16384       // up to 261120 int
#define HPART_OFF    1064960     // KSPLIT*1024*768 f32 = 12 MB

// ================= split-K GEMM (R3-proven) =================
// 64x64 tile, K-seg 192, 256 thr, 4x4 micro. hpart[z][m][n] = partial x.W1^T.
// Block (0,0,0) thread 0/1 also zero candCnt/pairCnt (ws is 0xAA-poisoned).
__global__ __launch_bounds__(256) void gemm_k_kernel(
    const float* __restrict__ x, const float* __restrict__ W1,
    float* __restrict__ hpart, int* __restrict__ counters)
{
    __shared__ float As[16][68];
    __shared__ float Bs[16][68];

    if (blockIdx.x == 0 && blockIdx.y == 0 && blockIdx.z == 0 && threadIdx.x < 2)
        counters[threadIdx.x] = 0;

    const int m0 = blockIdx.x * 64;
    const int n0 = blockIdx.y * 64;
    const int kb = blockIdx.z * KSEG;
    const int t  = threadIdx.x;
    const int tm = t & 15;
    const int tn = t >> 4;
    const int r  = t >> 2;        // 0..63
    const int c4 = (t & 3) * 4;   // 0,4,8,12

    float acc[4][4] = {};

    for (int k0 = kb; k0 < kb + KSEG; k0 += 16) {
        float4 av = *(const float4*)(x  + (size_t)(m0 + r) * HDIM + k0 + c4);
        float4 bv = *(const float4*)(W1 + (size_t)(n0 + r) * HDIM + k0 + c4);
        As[c4+0][r] = av.x; As[c4+1][r] = av.y; As[c4+2][r] = av.z; As[c4+3][r] = av.w;
        Bs[c4+0][r] = bv.x; Bs[c4+1][r] = bv.y; Bs[c4+2][r] = bv.z; Bs[c4+3][r] = bv.w;
        __syncthreads();
        #pragma unroll
        for (int kk = 0; kk < 16; ++kk) {
            float a[4], b[4];
            #pragma unroll
            for (int i = 0; i < 4; ++i) a[i] = As[kk][tm * 4 + i];
            #pragma unroll
            for (int j = 0; j < 4; ++j) b[j] = Bs[kk][tn * 4 + j];
            #pragma unroll
            for (int i = 0; i < 4; ++i)
                #pragma unroll
                for (int j = 0; j < 4; ++j)
                    acc[i][j] += a[i] * b[j];
        }
        __syncthreads();
    }

    // direct float4 stores: per instr, 16 rows x 64B full lines (coalesced)
    float* dst = hpart + (size_t)blockIdx.z * (M_ROWS * HDIM);
    #pragma unroll
    for (int i = 0; i < 4; ++i) {
        float4 v = make_float4(acc[i][0], acc[i][1], acc[i][2], acc[i][3]);
        *(float4*)(dst + (size_t)(m0 + tm * 4 + i) * HDIM + n0 + tn * 4) = v;
    }
}

// reduce KSPLIT partials, relu.w2, decide cand. One block per row m. (R3-proven)
__global__ __launch_bounds__(256) void span_cand_kernel(
    const float* __restrict__ hpart, const float* __restrict__ b1,
    const float* __restrict__ w2row, const float* __restrict__ b2,
    int* __restrict__ candCount, int* __restrict__ candIdx,
    int* __restrict__ candSlot)
{
    const int m = blockIdx.x;
    const int t = threadIdx.x;
    float p = 0.f;
    for (int n = t; n < HDIM; n += 256) {
        float v = hpart[(size_t)m * HDIM + n]
                + hpart[(size_t)(M_ROWS * HDIM) + (size_t)m * HDIM + n]
                + hpart[(size_t)(2 * M_ROWS * HDIM) + (size_t)m * HDIM + n]
                + hpart[(size_t)(3 * M_ROWS * HDIM) + (size_t)m * HDIM + n];
        v += b1[n];
        v = v > 0.f ? v : 0.f;
        p += v * w2row[n];
    }
    __shared__ float wred[4];
    #pragma unroll
    for (int off = 32; off > 0; off >>= 1) p += __shfl_down(p, off, 64);
    if ((t & 63) == 0) wred[t >> 6] = p;
    __syncthreads();
    if (t == 0) {
        float s = wred[0] + wred[1] + wred[2] + wred[3] + b2[0];
        if (s > 0.5f) {
            int sl = atomicAdd(candCount, 1);
            if (sl < MAXC) { candIdx[sl] = m; candSlot[m] = sl; }
            else candSlot[m] = -1;
        } else {
            candSlot[m] = -1;
        }
    }
}

// ================= hab: k-split across blocks (R3-proven) =================
// work item = (slot, kc): block computes ha/hb[slot][kc*16 .. kc*16+15].
__global__ __launch_bounds__(256) void hab_kernel(
    const float* __restrict__ x, const float* __restrict__ Wp1,
    const int* __restrict__ candCount, const int* __restrict__ candIdx,
    float* __restrict__ ha, float* __restrict__ hb)
{
    __shared__ float xs[HDIM];
    __shared__ float red[2][KCHUNK][17];
    int nc = *candCount; if (nc > MAXC) nc = MAXC;
    const int nitems = nc * NKC;
    const int kk  = threadIdx.x >> 4;
    const int hb0 = (threadIdx.x & 15) * 4;

    for (int item = blockIdx.x; item < nitems; item += gridDim.x) {
        int slot = item / NKC;
        int kc   = item % NKC;
        int row  = candIdx[slot];

        for (int h = threadIdx.x; h < HDIM; h += 256)
            xs[h] = x[(size_t)row * HDIM + h];
        __syncthreads();

        int k = kc * KCHUNK + kk;
        const float* wr = Wp1 + (size_t)k * (2 * HDIM);
        float sa = 0.f, sb = 0.f;
        #pragma unroll
        for (int h = hb0; h < HDIM; h += 64) {
            float4 xv = *(const float4*)(xs + h);
            float4 wa = *(const float4*)(wr + h);
            float4 wb = *(const float4*)(wr + HDIM + h);
            sa += xv.x * wa.x + xv.y * wa.y + xv.z * wa.z + xv.w * wa.w;
            sb += xv.x * wb.x + xv.y * wb.y + xv.z * wb.z + xv.w * wb.w;
        }
        red[0][kk][threadIdx.x & 15] = sa;
        red[1][kk][threadIdx.x & 15] = sb;
        __syncthreads();

        if (threadIdx.x < 32) {
            int which = threadIdx.x >> 4;
            int kk2   = threadIdx.x & 15;
            float s = 0.f;
            #pragma unroll
            for (int g = 0; g < 16; ++g) s += red[which][kk2][g];
            float* dst = which == 0 ? ha : hb;
            dst[(size_t)slot * HDIM + kc * KCHUNK + kk2] = s;
        }
        __syncthreads();
    }
}

// ================= build valid pair list (R3-proven) =================
__global__ void pairs_kernel(const int* __restrict__ candSlot,
                             int* __restrict__ pairCount, int* __restrict__ pairList)
{
    int idx = blockIdx.x * 256 + threadIdx.x;
    int b = idx >> 16;
    int i = (idx >> 8) & 255;
    int j = idx & 255;
    if (i == j) return;
    if (candSlot[b * 256 + i] >= 0 && candSlot[b * 256 + j] >= 0) {
        int p = atomicAdd(pairCount, 1);
        pairList[p] = idx;
    }
}

// ================= sparse pair logits (R3-proven) =================
__global__ __launch_bounds__(256) void pair_kernel(
    const float* __restrict__ ha, const float* __restrict__ hb,
    const float* __restrict__ bp1, const float* __restrict__ Wp2,
    const float* __restrict__ bp2, const int* __restrict__ candSlot,
    const int* __restrict__ pairCount, const int* __restrict__ pairList,
    float* __restrict__ out)
{
    __shared__ float v[HDIM];
    __shared__ float red[4][PDIM + 2];
    const int np = *pairCount;
    const int t = threadIdx.x;
    for (int p = blockIdx.x; p < np; p += gridDim.x) {
        int idx = pairList[p];
        int b = idx >> 16;
        int i = (idx >> 8) & 255;
        int j = idx & 255;
        int si = candSlot[b * 256 + i];
        int sj = candSlot[b * 256 + j];
        if (t < 192) {
            float4 a4 = *(const float4*)(ha + (size_t)si * HDIM + t * 4);
            float4 b4 = *(const float4*)(hb + (size_t)sj * HDIM + t * 4);
            float4 c4 = *(const float4*)(bp1 + t * 4);
            float4 r;
            r.x = a4.x + b4.x + c4.x; r.x = r.x > 0.f ? r.x : 0.f;
            r.y = a4.y + b4.y + c4.y; r.y = r.y > 0.f ? r.y : 0.f;
            r.z = a4.z + b4.z + c4.z; r.z = r.z > 0.f ? r.z : 0.f;
            r.w = a4.w + b4.w + c4.w; r.w = r.w > 0.f ? r.w : 0.f;
            *(float4*)(v + t * 4) = r;
        }
        __syncthreads();
        if (t < 216) {
            int pp  = t % PDIM;
            int seg = t / PDIM;               // 0..3, h-range 192 each
            const float* w = Wp2 + (size_t)pp * HDIM + seg * 192;
            const float* vv = v + seg * 192;
            float s = 0.f;
            for (int h = 0; h < 192; h += 4) {
                float4 a = *(const float4*)(vv + h);
                float4 b2_ = *(const float4*)(w + h);
                s += a.x * b2_.x + a.y * b2_.y + a.z * b2_.z + a.w * b2_.w;
            }
            red[seg][pp] = s;
        }
        __syncthreads();
        if (t < PDIM)
            out[(size_t)idx * PDIM + t] = red[0][t] + red[1][t] + red[2][t] + red[3][t] + bp2[t];
        __syncthreads();
    }
}

extern "C" void kernel_launch(void* const* d_in, const int* in_sizes, int n_in,
                              void* d_out, int out_size, void* d_ws, size_t ws_size,
                              hipStream_t stream) {
    const float* x   = (const float*)d_in[0];
    const float* W1s = (const float*)d_in[1];
    const float* b1s = (const float*)d_in[2];
    const float* W2s = (const float*)d_in[3];
    const float* b2s = (const float*)d_in[4];
    const float* Wp1 = (const float*)d_in[5];
    const float* bp1 = (const float*)d_in[6];
    const float* Wp2 = (const float*)d_in[7];
    const float* bp2 = (const float*)d_in[8];

    char* ws = (char*)d_ws;
    int*   counters = (int*)(ws + CANDCNT_OFF);   // [0]=candCnt, [1]=pairCnt
    int*   candCnt  = counters;
    int*   pairCnt  = counters + 1;
    int*   candIdx  = (int*)(ws + CANDIDX_OFF);
    int*   candSlot = (int*)(ws + CANDSLOT_OFF);
    int*   pairList = (int*)(ws + PAIR_OFF);
    float* hpart    = (float*)(ws + HPART_OFF);
    float* ha       = hpart + (size_t)KSPLIT * M_ROWS * HDIM;
    float* hb       = ha + (size_t)MAXC * HDIM;
    float* out = (float*)d_out;

    // zero output (masked regions must be exactly 0)
    hipMemsetAsync(out, 0, (size_t)out_size * sizeof(float), stream);

    dim3 g(M_ROWS / 64, HDIM / 64, KSPLIT);
    gemm_k_kernel<<<g, 256, 0, stream>>>(x, W1s, hpart, counters);

    span_cand_kernel<<<M_ROWS, 256, 0, stream>>>(hpart, b1s, W2s, b2s,
                                                 candCnt, candIdx, candSlot);

    hab_kernel<<<2048, 256, 0, stream>>>(x, Wp1, candCnt, candIdx, ha, hb);

    pairs_kernel<<<1024, 256, 0, stream>>>(candSlot, pairCnt, pairList);

    pair_kernel<<<512, 256, 0, stream>>>(ha, hb, bp1, Wp2, bp2,
                                         candSlot, pairCnt, pairList, out);
}